// Round 1
// 8773.432 us; speedup vs baseline: 1.8325x; 1.8325x over previous
//
#include <hip/hip_runtime.h>

typedef _Float16 h2 __attribute__((ext_vector_type(2)));
typedef float f2 __attribute__((ext_vector_type(2)));

static constexpr int T_LEN = 1024;
static constexpr int RD    = 8192;
static constexpr int SD    = 128;
static constexpr int NBLK  = 256;
static constexpr int GRPS  = 8;
static constexpr int BLK_PER_GRP = NBLK / GRPS;  // 32
// Resident-W layout: per wave, even row (16 uint4-chunks/lane) in VGPRs,
// odd row: NL chunks in LDS, (16-NL) chunks stay global (L2-resident).
static constexpr int NL = 9;                         // LDS chunks of odd row
static constexpr int LDS_BYTES = 16 * NL * 1024;     // 147456 B = 144 KB
// bar layout (ints): group g arrive @ [g*16], super @ [128], generation @ [160]

// ---------- fdot2 wrapper ----------
__device__ __forceinline__ float dot2(unsigned int a, unsigned int b, float c) {
#if __has_builtin(__builtin_amdgcn_fdot2)
  return __builtin_amdgcn_fdot2(__builtin_bit_cast(h2, a), __builtin_bit_cast(h2, b), c, false);
#else
  h2 ha = __builtin_bit_cast(h2, a), hb = __builtin_bit_cast(h2, b);
  return c + (float)ha[0] * (float)hb[0] + (float)ha[1] * (float)hb[1];
#endif
}

// ---------- W_res fp32 -> fp16 ----------
__global__ void cvt_w_kernel(const float* __restrict__ w, unsigned short* __restrict__ w16, long n) {
  long i = ((long)blockIdx.x * blockDim.x + threadIdx.x) * 4;
  long stride = (long)gridDim.x * blockDim.x * 4;
  for (; i < n; i += stride) {
    float f0 = __builtin_nontemporal_load(w + i);
    float f1 = __builtin_nontemporal_load(w + i + 1);
    float f2_ = __builtin_nontemporal_load(w + i + 2);
    float f3 = __builtin_nontemporal_load(w + i + 3);
    h2 p0 = { (_Float16)f0, (_Float16)f1 };
    h2 p1 = { (_Float16)f2_, (_Float16)f3 };
    uint2 o;
    o.x = __builtin_bit_cast(unsigned int, p0);
    o.y = __builtin_bit_cast(unsigned int, p1);
    *(uint2*)(w16 + i) = o;
  }
}

// ---------- r0 fp32 -> fp16 slot 0, zero barrier block ----------
__global__ void cvt_r16_kernel(const float* __restrict__ r, unsigned short* __restrict__ rh,
                               int* __restrict__ bar) {
  int i = blockIdx.x * 256 + threadIdx.x;
  _Float16 h = (_Float16)r[i];
  rh[i] = __builtin_bit_cast(unsigned short, h);
  if (blockIdx.x == 0) bar[threadIdx.x] = 0;
}

// ---------- r0 fp32 -> fp32 (fallback), zero barrier ----------
__global__ void cvt_r32_kernel(const float* __restrict__ r, float* __restrict__ rf,
                               int* __restrict__ bar) {
  int i = blockIdx.x * 256 + threadIdx.x;
  rf[i] = r[i];
  if (blockIdx.x == 0) bar[threadIdx.x] = 0;
}

// ---------- in_proj = in_seq @ W_in^T + b_res -> d_out ----------
__global__ void in_proj_kernel(const float* __restrict__ in_seq,
                               const float* __restrict__ W_in,
                               const float* __restrict__ b_res,
                               float* __restrict__ out) {
  __shared__ float u[8 * SD];
  const int tid = threadIdx.x;
  const int ib = blockIdx.x;
  const int tb = blockIdx.y;
  ((float4*)u)[tid] = ((const float4*)(in_seq + (size_t)tb * 8 * SD))[tid];
  __syncthreads();
  const int i = ib * 256 + tid;
  const float4* wrow = (const float4*)(W_in + (size_t)i * SD);
  float b = b_res[i];
  float acc[8];
#pragma unroll
  for (int t = 0; t < 8; ++t) acc[t] = b;
  for (int kc = 0; kc < SD / 4; ++kc) {
    float4 w = wrow[kc];
#pragma unroll
    for (int t = 0; t < 8; ++t) {
      float4 uv = ((const float4*)(u + t * SD))[kc];
      acc[t] += w.x * uv.x + w.y * uv.y + w.z * uv.z + w.w * uv.w;
    }
  }
#pragma unroll
  for (int t = 0; t < 8; ++t)
    out[(size_t)(tb * 8 + t) * RD + i] = acc[t];
}

// ---------- resident-W rollout ----------
// Even row fully in VGPRs (64 regs/lane). Odd row: NL chunks in LDS,
// 16-NL chunks from global (L2-resident: 112 KB/CU -> 3.5 MB/XCD).
// Per-step off-CU traffic: r (16 KB) + odd-row L2 chunks only.
// Sync: identical to the proven MULTI scheme (relaxed agent atomics,
// cold-line freshness, tree barrier, s_sleep spin).
__global__ __launch_bounds__(1024, 4) void rollout_resident(
    const unsigned short* __restrict__ W, unsigned short* __restrict__ rseq,
    float* __restrict__ io, int* __restrict__ bar) {
  extern __shared__ char smem_raw[];
  __shared__ int lds_cnt;
  const int lane = threadIdx.x & 63;
  const int wave = threadIdx.x >> 6;
  const int row0 = blockIdx.x * 32 + wave * 2;

  const uint4* w0 = (const uint4*)(W + (size_t)row0 * RD);
  const uint4* w1 = w0 + RD / 8;

  // ---- persistent even-row registers (64 VGPRs) ----
  uint4 A[16];
#pragma unroll
  for (int k = 0; k < 16; ++k) A[k] = w0[k * 64 + lane];

  // ---- stage odd-row chunks 0..NL-1 into LDS ----
  uint4* bl = (uint4*)smem_raw + wave * (NL * 64) + lane;
#pragma unroll
  for (int c = 0; c < NL; ++c) bl[c * 64] = w1[c * 64 + lane];

  if (threadIdx.x == 0) lds_cnt = 0;
  __syncthreads();

  uint4 rv[4], bv[2];

#pragma unroll 1
  for (int t = 0; t < T_LEN; ++t) {
    const uint4* rh = (const uint4*)(rseq + (size_t)t * RD);
#pragma unroll
    for (int k = 0; k < 4; ++k) rv[k] = rh[k * 64 + lane];   // r preamble
    bv[0] = bl[0];
    bv[1] = bl[64];
    float a0 = 0.f, a1 = 0.f;
#pragma unroll
    for (int j = 0; j < 16; ++j) {
      uint4 R = rv[j & 3];
      if (j < 12) rv[j & 3] = rh[(j + 4) * 64 + lane];
      uint4 Bv = bv[j & 1];
      if (j + 2 < 16) {
        if (j + 2 < NL) bv[j & 1] = bl[(j + 2) * 64];
        else            bv[j & 1] = w1[(j + 2) * 64 + lane];
      }
      a0 = dot2(A[j].x, R.x, a0); a0 = dot2(A[j].y, R.y, a0);
      a0 = dot2(A[j].z, R.z, a0); a0 = dot2(A[j].w, R.w, a0);
      a1 = dot2(Bv.x, R.x, a1);   a1 = dot2(Bv.y, R.y, a1);
      a1 = dot2(Bv.z, R.z, a1);   a1 = dot2(Bv.w, R.w, a1);
    }
#pragma unroll
    for (int off = 32; off; off >>= 1) {
      a0 += __shfl_xor(a0, off);
      a1 += __shfl_xor(a1, off);
    }
    if (lane == 0) {
      float2 p = *(const float2*)(io + (size_t)t * RD + row0);
      float v0 = tanhf(a0 + p.x);
      float v1 = tanhf(a1 + p.y);
      f2 vv = { v0, v1 };
      __builtin_nontemporal_store(vv, (f2*)(io + (size_t)t * RD + row0));
      h2 hv = { (_Float16)v0, (_Float16)v1 };
      unsigned int bits = __builtin_bit_cast(unsigned int, hv);
      unsigned int* rdst = (unsigned int*)(rseq + (size_t)(t + 1) * RD + row0);
      __hip_atomic_store(rdst, bits, __ATOMIC_RELAXED, __HIP_MEMORY_SCOPE_AGENT);
    }
    asm volatile("" ::: "memory");
    __builtin_amdgcn_s_waitcnt(0x0F70);   // vmcnt(0): r-store at coherence point
    asm volatile("" ::: "memory");
    if (lane == 0) {
      int old = __hip_atomic_fetch_add(&lds_cnt, 1, __ATOMIC_RELAXED, __HIP_MEMORY_SCOPE_WORKGROUP);
      if (old == (t + 1) * 16 - 1) {      // last wave of block this step
        int g = blockIdx.x >> 5;
        int go = __hip_atomic_fetch_add(&bar[g * 16], 1, __ATOMIC_RELAXED, __HIP_MEMORY_SCOPE_AGENT);
        if (go == (t + 1) * BLK_PER_GRP - 1) {
          int so = __hip_atomic_fetch_add(&bar[128], 1, __ATOMIC_RELAXED, __HIP_MEMORY_SCOPE_AGENT);
          if (so == (t + 1) * GRPS - 1) {
            __hip_atomic_store(&bar[160], t + 1, __ATOMIC_RELAXED, __HIP_MEMORY_SCOPE_AGENT);
          }
        }
      }
    }
    if (wave == 0) {
      if (lane == 0) {
        while (__hip_atomic_load(&bar[160], __ATOMIC_RELAXED, __HIP_MEMORY_SCOPE_AGENT) <= t)
          __builtin_amdgcn_s_sleep(2);
      }
    }
    asm volatile("" ::: "memory");
    __builtin_amdgcn_s_barrier();
    asm volatile("" ::: "memory");
  }
}

// ---------- main rollout (streaming W; kept as fallback paths) ----------
template <bool MULTI>
__global__ __launch_bounds__(1024, 4) void rollout_kernel(
    const unsigned short* __restrict__ W, unsigned short* __restrict__ rseq,
    float* __restrict__ io, int* __restrict__ bar) {
  __shared__ int lds_cnt;
  const int lane = threadIdx.x & 63;
  const int wave = threadIdx.x >> 6;
  const int row0 = blockIdx.x * 32 + wave * 2;
  if (threadIdx.x == 0) lds_cnt = 0;
  __syncthreads();

  const uint4* w0 = (const uint4*)(W + (size_t)row0 * RD);
  const uint4* w1 = w0 + RD / 8;

  uint4 wa[4], wb[4], rv[4];
#pragma unroll
  for (int k = 0; k < 4; ++k) {          // initial W prefetch, iters 0..3
    int idx = k * 64 + lane;
    wa[k] = w0[idx]; wb[k] = w1[idx];
  }

#pragma unroll 1
  for (int t = 0; t < T_LEN; ++t) {
    const uint4* rh = (const uint4*)(rseq + (size_t)(MULTI ? t : (t & 1)) * RD);
#pragma unroll
    for (int k = 0; k < 4; ++k) rv[k] = rh[k * 64 + lane];   // r preamble
    float a0 = 0.f, a1 = 0.f;
#pragma unroll
    for (int j = 0; j < 16; ++j) {
      int k = j & 3;
      uint4 A = wa[k], B = wb[k], R = rv[k];
      if (j < 12) {
        int idx = (j + 4) * 64 + lane;
        rv[k] = rh[idx]; wa[k] = w0[idx]; wb[k] = w1[idx];
      }
      a0 = dot2(A.x, R.x, a0); a0 = dot2(A.y, R.y, a0);
      a0 = dot2(A.z, R.z, a0); a0 = dot2(A.w, R.w, a0);
      a1 = dot2(B.x, R.x, a1); a1 = dot2(B.y, R.y, a1);
      a1 = dot2(B.z, R.z, a1); a1 = dot2(B.w, R.w, a1);
    }
#pragma unroll
    for (int off = 32; off; off >>= 1) {
      a0 += __shfl_xor(a0, off);
      a1 += __shfl_xor(a1, off);
    }
    if (lane == 0) {
      float2 p = *(const float2*)(io + (size_t)t * RD + row0);
      float v0 = tanhf(a0 + p.x);
      float v1 = tanhf(a1 + p.y);
      f2 vv = { v0, v1 };
      __builtin_nontemporal_store(vv, (f2*)(io + (size_t)t * RD + row0));
      h2 hv = { (_Float16)v0, (_Float16)v1 };
      unsigned int bits = __builtin_bit_cast(unsigned int, hv);
      unsigned int* rdst = (unsigned int*)(rseq + (size_t)(MULTI ? (t + 1) : ((t + 1) & 1)) * RD + row0);
      __hip_atomic_store(rdst, bits, __ATOMIC_RELAXED, __HIP_MEMORY_SCOPE_AGENT);
    }
    asm volatile("" ::: "memory");
    __builtin_amdgcn_s_waitcnt(0x0F70);   // vmcnt(0): r-store at coherence point
    asm volatile("" ::: "memory");
    if (lane == 0) {
      int old = __hip_atomic_fetch_add(&lds_cnt, 1, __ATOMIC_RELAXED, __HIP_MEMORY_SCOPE_WORKGROUP);
      if (old == (t + 1) * 16 - 1) {      // last wave of block this step
        int g = blockIdx.x >> 5;
        int go = __hip_atomic_fetch_add(&bar[g * 16], 1, __ATOMIC_RELAXED, __HIP_MEMORY_SCOPE_AGENT);
        if (go == (t + 1) * BLK_PER_GRP - 1) {
          int so = __hip_atomic_fetch_add(&bar[128], 1, __ATOMIC_RELAXED, __HIP_MEMORY_SCOPE_AGENT);
          if (so == (t + 1) * GRPS - 1) {
            __hip_atomic_store(&bar[160], t + 1, __ATOMIC_RELAXED, __HIP_MEMORY_SCOPE_AGENT);
          }
        }
      }
    }
    if (wave != 0) {
      // next-step W prefetch (same addresses every step) in flight across the spin
#pragma unroll
      for (int k = 0; k < 4; ++k) {
        int idx = k * 64 + lane;
        wa[k] = w0[idx]; wb[k] = w1[idx];
      }
      asm volatile("" ::: "memory");
      __builtin_amdgcn_s_barrier();
      asm volatile("" ::: "memory");
    } else {
      if (lane == 0) {
        while (__hip_atomic_load(&bar[160], __ATOMIC_RELAXED, __HIP_MEMORY_SCOPE_AGENT) <= t)
          __builtin_amdgcn_s_sleep(2);
        if (!MULTI)
          (void)__hip_atomic_load(&bar[160], __ATOMIC_ACQUIRE, __HIP_MEMORY_SCOPE_AGENT);
      }
      asm volatile("" ::: "memory");
      __builtin_amdgcn_s_barrier();
      asm volatile("" ::: "memory");
#pragma unroll
      for (int k = 0; k < 4; ++k) {
        int idx = k * 64 + lane;
        wa[k] = w0[idx]; wb[k] = w1[idx];
      }
    }
  }
}

// ---------- fp32 fallback (tiny ws; round-3 proven structure) ----------
__device__ __forceinline__ void grid_barrier_f32(int* bar, int t, int nblk) {
  __syncthreads();
  if (threadIdx.x == 0) {
    int arrived = __hip_atomic_fetch_add(&bar[0], 1, __ATOMIC_RELEASE, __HIP_MEMORY_SCOPE_AGENT);
    if (arrived == (t + 1) * nblk - 1) {
      __hip_atomic_store(&bar[32], t + 1, __ATOMIC_RELEASE, __HIP_MEMORY_SCOPE_AGENT);
    } else {
      while (__hip_atomic_load(&bar[32], __ATOMIC_RELAXED, __HIP_MEMORY_SCOPE_AGENT) <= t)
        __builtin_amdgcn_s_sleep(2);
    }
    (void)__hip_atomic_load(&bar[32], __ATOMIC_ACQUIRE, __HIP_MEMORY_SCOPE_AGENT);
  }
  __syncthreads();
}

__global__ __launch_bounds__(1024, 4) void rollout_f32(const float* __restrict__ W,
                                                       float* __restrict__ rbuf,
                                                       float* __restrict__ io,
                                                       int* __restrict__ bar) {
  const int lane = threadIdx.x & 63;
  const int wave = threadIdx.x >> 6;
  const int row0 = blockIdx.x * 32 + wave * 2;
  const int nblk = gridDim.x;
  for (int t = 0; t < T_LEN; ++t) {
    float a0 = 0.f, a1 = 0.f;
    const float4* w0 = (const float4*)(W + (size_t)row0 * RD);
    const float4* w1 = w0 + RD / 4;
    const float4* rf = (const float4*)(rbuf + (size_t)(t & 1) * RD);
    float4 wa[4], wb[4], rv[4];
#pragma unroll
    for (int k = 0; k < 4; ++k) {
      int idx = k * 64 + lane;
      rv[k] = rf[idx]; wa[k] = w0[idx]; wb[k] = w1[idx];
    }
#pragma unroll
    for (int j = 0; j < 32; ++j) {
      int k = j & 3;
      float4 A = wa[k], B = wb[k], R = rv[k];
      if (j < 28) {
        int idx = (j + 4) * 64 + lane;
        rv[k] = rf[idx]; wa[k] = w0[idx]; wb[k] = w1[idx];
      }
      a0 += A.x * R.x + A.y * R.y + A.z * R.z + A.w * R.w;
      a1 += B.x * R.x + B.y * R.y + B.z * R.z + B.w * R.w;
    }
#pragma unroll
    for (int off = 32; off; off >>= 1) {
      a0 += __shfl_xor(a0, off);
      a1 += __shfl_xor(a1, off);
    }
    if (lane == 0) {
      float2 p = *(const float2*)(io + (size_t)t * RD + row0);
      float v0 = tanhf(a0 + p.x);
      float v1 = tanhf(a1 + p.y);
      f2 vv = { v0, v1 };
      __builtin_nontemporal_store(vv, (f2*)(io + (size_t)t * RD + row0));
      float* rn = rbuf + (size_t)((t + 1) & 1) * RD;
      *(f2*)(rn + row0) = vv;
    }
    grid_barrier_f32(bar, t, nblk);
  }
}

extern "C" void kernel_launch(void* const* d_in, const int* in_sizes, int n_in,
                              void* d_out, int out_size, void* d_ws, size_t ws_size,
                              hipStream_t stream) {
  const float* in_seq    = (const float*)d_in[0];
  const float* res_state = (const float*)d_in[1];
  const float* W_in      = (const float*)d_in[2];
  const float* W_res     = (const float*)d_in[3];
  const float* b_res     = (const float*)d_in[4];
  float* out = (float*)d_out;

  hipLaunchKernelGGL(in_proj_kernel, dim3(32, 128), dim3(256), 0, stream,
                     in_seq, W_in, b_res, out);

  const size_t w16_bytes   = (size_t)RD * RD * 2;                 // 128 MB
  const size_t rseq_multi  = (size_t)(T_LEN + 1) * RD * 2;        // 16.8 MB
  const size_t rseq_double = (size_t)2 * RD * 2;
  const size_t bar_bytes   = 1024 * 4;

  if (ws_size >= w16_bytes + rseq_multi + bar_bytes) {
    unsigned short* w16  = (unsigned short*)d_ws;
    unsigned short* rseq = (unsigned short*)((char*)d_ws + w16_bytes);
    int* bar = (int*)((char*)d_ws + w16_bytes + rseq_multi);
    hipLaunchKernelGGL(cvt_w_kernel, dim3(8192), dim3(256), 0, stream,
                       W_res, w16, (long)RD * RD);
    hipLaunchKernelGGL(cvt_r16_kernel, dim3(RD / 256), dim3(256), 0, stream,
                       res_state, rseq, bar);
    const unsigned short* Wv = w16;
    unsigned short* rv = rseq;
    float* iov = out;
    int* barv = bar;
    void* args[4] = { &Wv, &rv, &iov, &barv };

    static int attr_done = 0;
    if (!attr_done) {
      (void)hipFuncSetAttribute((const void*)rollout_resident,
                                hipFuncAttributeMaxDynamicSharedMemorySize,
                                LDS_BYTES);
      attr_done = 1;
    }
    hipError_t err = hipLaunchCooperativeKernel(rollout_resident, dim3(NBLK),
                                                dim3(1024), args,
                                                (size_t)LDS_BYTES, stream);
    if (err != hipSuccess) {
      // dynamic-LDS refused: fall back to proven streaming kernel
      (void)hipLaunchCooperativeKernel(rollout_kernel<true>, dim3(NBLK),
                                       dim3(1024), args, 0, stream);
    }
  } else if (ws_size >= w16_bytes + rseq_double + bar_bytes) {
    unsigned short* w16  = (unsigned short*)d_ws;
    unsigned short* rseq = (unsigned short*)((char*)d_ws + w16_bytes);
    int* bar = (int*)((char*)d_ws + w16_bytes + rseq_double);
    hipLaunchKernelGGL(cvt_w_kernel, dim3(8192), dim3(256), 0, stream,
                       W_res, w16, (long)RD * RD);
    hipLaunchKernelGGL(cvt_r16_kernel, dim3(RD / 256), dim3(256), 0, stream,
                       res_state, rseq, bar);
    const unsigned short* Wv = w16;
    unsigned short* rv = rseq;
    float* iov = out;
    int* barv = bar;
    void* args[4] = { &Wv, &rv, &iov, &barv };
    (void)hipLaunchCooperativeKernel(rollout_kernel<false>, dim3(NBLK), dim3(1024),
                                     args, 0, stream);
  } else {
    float* rbuf = (float*)d_ws;
    int* bar = (int*)((char*)d_ws + (size_t)2 * RD * 4);
    hipLaunchKernelGGL(cvt_r32_kernel, dim3(RD / 256), dim3(256), 0, stream,
                       res_state, rbuf, bar);
    const float* Wv = W_res;
    float* rv = rbuf;
    float* iov = out;
    int* barv = bar;
    void* args[4] = { &Wv, &rv, &iov, &barv };
    (void)hipLaunchCooperativeKernel(rollout_f32, dim3(NBLK), dim3(1024),
                                     args, 0, stream);
  }
}

// Round 2
// 4855.188 us; speedup vs baseline: 3.3114x; 1.8070x over previous
//
#include <hip/hip_runtime.h>

typedef _Float16 h2 __attribute__((ext_vector_type(2)));
typedef float f2 __attribute__((ext_vector_type(2)));

static constexpr int T_LEN = 1024;
static constexpr int RD    = 8192;
static constexpr int SD    = 128;
static constexpr int NBLK  = 256;
static constexpr int GRPS  = 8;
static constexpr int BLK_PER_GRP = NBLK / GRPS;  // 32
static constexpr unsigned int SENT = 0x7FFF7FFFu;   // fp16 NaN pair — unreachable by tanh/randn data
// rollout_flow LDS: W odd rows 16 waves x 8 chunks x 1KB = 128 KB, then r buffer 16 KB
static constexpr int WL_CHUNKS = 8;
static constexpr int WL_BYTES  = 16 * WL_CHUNKS * 64 * 16;   // 131072
static constexpr int LDS_BYTES = WL_BYTES + RD * 2;          // 147456 = 144 KB
// bar layout (ints): group g arrive @ [g*16], super @ [128], generation @ [160] (fallback path only)

// ---------- fdot2 wrapper ----------
__device__ __forceinline__ float dot2(unsigned int a, unsigned int b, float c) {
#if __has_builtin(__builtin_amdgcn_fdot2)
  return __builtin_amdgcn_fdot2(__builtin_bit_cast(h2, a), __builtin_bit_cast(h2, b), c, false);
#else
  h2 ha = __builtin_bit_cast(h2, a), hb = __builtin_bit_cast(h2, b);
  return c + (float)ha[0] * (float)hb[0] + (float)ha[1] * (float)hb[1];
#endif
}

// ---------- W_res fp32 -> fp16 ----------
__global__ void cvt_w_kernel(const float* __restrict__ w, unsigned short* __restrict__ w16, long n) {
  long i = ((long)blockIdx.x * blockDim.x + threadIdx.x) * 4;
  long stride = (long)gridDim.x * blockDim.x * 4;
  for (; i < n; i += stride) {
    float f0 = __builtin_nontemporal_load(w + i);
    float f1 = __builtin_nontemporal_load(w + i + 1);
    float f2_ = __builtin_nontemporal_load(w + i + 2);
    float f3 = __builtin_nontemporal_load(w + i + 3);
    h2 p0 = { (_Float16)f0, (_Float16)f1 };
    h2 p1 = { (_Float16)f2_, (_Float16)f3 };
    uint2 o;
    o.x = __builtin_bit_cast(unsigned int, p0);
    o.y = __builtin_bit_cast(unsigned int, p1);
    *(uint2*)(w16 + i) = o;
  }
}

// ---------- fill rseq slots 1..T with sentinel ----------
__global__ void fill_sentinel_kernel(unsigned int* __restrict__ p, long nwords) {
  long i = (long)blockIdx.x * blockDim.x + threadIdx.x;
  long stride = (long)gridDim.x * blockDim.x;
  for (; i < nwords; i += stride) p[i] = SENT;
}

// ---------- r0 fp32 -> fp16 slot 0, zero barrier block ----------
__global__ void cvt_r16_kernel(const float* __restrict__ r, unsigned short* __restrict__ rh,
                               int* __restrict__ bar) {
  int i = blockIdx.x * 256 + threadIdx.x;
  _Float16 h = (_Float16)r[i];
  rh[i] = __builtin_bit_cast(unsigned short, h);
  if (blockIdx.x == 0) bar[threadIdx.x] = 0;
}

// ---------- r0 fp32 -> fp32 (fallback), zero barrier ----------
__global__ void cvt_r32_kernel(const float* __restrict__ r, float* __restrict__ rf,
                               int* __restrict__ bar) {
  int i = blockIdx.x * 256 + threadIdx.x;
  rf[i] = r[i];
  if (blockIdx.x == 0) bar[threadIdx.x] = 0;
}

// ---------- in_proj = in_seq @ W_in^T + b_res -> d_out ----------
__global__ void in_proj_kernel(const float* __restrict__ in_seq,
                               const float* __restrict__ W_in,
                               const float* __restrict__ b_res,
                               float* __restrict__ out) {
  __shared__ float u[8 * SD];
  const int tid = threadIdx.x;
  const int ib = blockIdx.x;
  const int tb = blockIdx.y;
  ((float4*)u)[tid] = ((const float4*)(in_seq + (size_t)tb * 8 * SD))[tid];
  __syncthreads();
  const int i = ib * 256 + tid;
  const float4* wrow = (const float4*)(W_in + (size_t)i * SD);
  float b = b_res[i];
  float acc[8];
#pragma unroll
  for (int t = 0; t < 8; ++t) acc[t] = b;
  for (int kc = 0; kc < SD / 4; ++kc) {
    float4 w = wrow[kc];
#pragma unroll
    for (int t = 0; t < 8; ++t) {
      float4 uv = ((const float4*)(u + t * SD))[kc];
      acc[t] += w.x * uv.x + w.y * uv.y + w.z * uv.z + w.w * uv.w;
    }
  }
#pragma unroll
  for (int t = 0; t < 8; ++t)
    out[(size_t)(tb * 8 + t) * RD + i] = acc[t];
}

// ---------- dataflow rollout: sentinel-poll r exchange, no grid barrier ----------
// Even row of each wave fully in regs (A[16]); odd row chunks 0..7 in LDS, 8..15
// from global (L2-resident). Per step: wave w poll-imports chunk w of r[t] from
// the slot buffer (agent-scope u64 loads; data IS the ready flag since fp16 NaN
// sentinel is unreachable), deposits it in LDS; 2 intra-block barriers; compute;
// lane0 fires the r[t+1] store (relaxed agent, write-through) and never waits.
__global__ __launch_bounds__(1024, 4) void rollout_flow(
    const unsigned short* __restrict__ W, unsigned short* __restrict__ rseq,
    float* __restrict__ io, int* __restrict__ bar) {
  extern __shared__ char smem_raw[];
  uint4* wlds = (uint4*)smem_raw;                       // [16][8][64]
  uint4* rbuf = (uint4*)(smem_raw + WL_BYTES);          // [16][64]
  const int lane = threadIdx.x & 63;
  const int wave = threadIdx.x >> 6;
  const int row0 = blockIdx.x * 32 + wave * 2;
  (void)bar;

  const uint4* w0 = (const uint4*)(W + (size_t)row0 * RD);
  const uint4* w1 = w0 + RD / 8;

  // persistent even-row registers
  uint4 A[16];
#pragma unroll
  for (int k = 0; k < 16; ++k) A[k] = w0[k * 64 + lane];

  // stage odd-row chunks 0..7 into this wave's private LDS region
  uint4* wl = wlds + wave * (WL_CHUNKS * 64) + lane;
#pragma unroll
  for (int c = 0; c < WL_CHUNKS; ++c) wl[c * 64] = w1[c * 64 + lane];

  // importer source offset: chunk `wave`, lane covers 16B -> 2 u64 words
  const size_t imp_off = (size_t)wave * 128 + (size_t)lane * 2;  // u64 units
  const unsigned long long* rseq64 = (const unsigned long long*)rseq;

  uint4 rv[4], bv[2];

#pragma unroll 1
  for (int t = 0; t < T_LEN; ++t) {
    // hoisted io prefetch (address independent of the reduction)
    float2 p;
    if (lane == 0) p = *(const float2*)(io + (size_t)t * RD + row0);

    // ---- phase A: poll-import chunk `wave` of r[t] ----
    const unsigned long long* src = rseq64 + (size_t)t * (RD / 4) + imp_off;
    unsigned long long x0 = __hip_atomic_load(src,     __ATOMIC_RELAXED, __HIP_MEMORY_SCOPE_AGENT);
    unsigned long long x1 = __hip_atomic_load(src + 1, __ATOMIC_RELAXED, __HIP_MEMORY_SCOPE_AGENT);
    while (__any((unsigned int)x0 == SENT || (unsigned int)(x0 >> 32) == SENT ||
                 (unsigned int)x1 == SENT || (unsigned int)(x1 >> 32) == SENT)) {
      __builtin_amdgcn_s_sleep(1);
      x0 = __hip_atomic_load(src,     __ATOMIC_RELAXED, __HIP_MEMORY_SCOPE_AGENT);
      x1 = __hip_atomic_load(src + 1, __ATOMIC_RELAXED, __HIP_MEMORY_SCOPE_AGENT);
    }
    uint4 rx;
    rx.x = (unsigned int)x0; rx.y = (unsigned int)(x0 >> 32);
    rx.z = (unsigned int)x1; rx.w = (unsigned int)(x1 >> 32);
    rbuf[wave * 64 + lane] = rx;
    __syncthreads();                       // all 16 chunks now in LDS

    // ---- phase B: compute from LDS ----
#pragma unroll
    for (int k = 0; k < 4; ++k) rv[k] = rbuf[k * 64 + lane];
    bv[0] = wl[0];
    bv[1] = wl[64];
    float a0 = 0.f, a1 = 0.f;
#pragma unroll
    for (int j = 0; j < 16; ++j) {
      uint4 R = rv[j & 3];
      if (j < 12) rv[j & 3] = rbuf[(j + 4) * 64 + lane];
      uint4 Bv = bv[j & 1];
      if (j + 2 < 16) {
        if (j + 2 < WL_CHUNKS) bv[j & 1] = wl[(j + 2) * 64];
        else                   bv[j & 1] = w1[(j + 2) * 64 + lane];
      }
      a0 = dot2(A[j].x, R.x, a0); a0 = dot2(A[j].y, R.y, a0);
      a0 = dot2(A[j].z, R.z, a0); a0 = dot2(A[j].w, R.w, a0);
      a1 = dot2(Bv.x, R.x, a1);   a1 = dot2(Bv.y, R.y, a1);
      a1 = dot2(Bv.z, R.z, a1);   a1 = dot2(Bv.w, R.w, a1);
    }
#pragma unroll
    for (int off = 32; off; off >>= 1) {
      a0 += __shfl_xor(a0, off);
      a1 += __shfl_xor(a1, off);
    }
    if (lane == 0) {
      float v0 = tanhf(a0 + p.x);
      float v1 = tanhf(a1 + p.y);
      f2 vv = { v0, v1 };
      __builtin_nontemporal_store(vv, (f2*)(io + (size_t)t * RD + row0));
      h2 hv = { (_Float16)v0, (_Float16)v1 };
      unsigned int bits = __builtin_bit_cast(unsigned int, hv);
      unsigned int* rdst = (unsigned int*)(rseq + (size_t)(t + 1) * RD + row0);
      __hip_atomic_store(rdst, bits, __ATOMIC_RELAXED, __HIP_MEMORY_SCOPE_AGENT);
      // fire and forget: the store is the ready flag for step t+1 consumers
    }
    __syncthreads();                       // protect rbuf reuse next step
  }
}

// ---------- streaming rollout (fallback; proven) ----------
template <bool MULTI>
__global__ __launch_bounds__(1024, 4) void rollout_kernel(
    const unsigned short* __restrict__ W, unsigned short* __restrict__ rseq,
    float* __restrict__ io, int* __restrict__ bar) {
  __shared__ int lds_cnt;
  const int lane = threadIdx.x & 63;
  const int wave = threadIdx.x >> 6;
  const int row0 = blockIdx.x * 32 + wave * 2;
  if (threadIdx.x == 0) lds_cnt = 0;
  __syncthreads();

  const uint4* w0 = (const uint4*)(W + (size_t)row0 * RD);
  const uint4* w1 = w0 + RD / 8;

  uint4 wa[4], wb[4], rv[4];
#pragma unroll
  for (int k = 0; k < 4; ++k) {
    int idx = k * 64 + lane;
    wa[k] = w0[idx]; wb[k] = w1[idx];
  }

#pragma unroll 1
  for (int t = 0; t < T_LEN; ++t) {
    const uint4* rh = (const uint4*)(rseq + (size_t)(MULTI ? t : (t & 1)) * RD);
#pragma unroll
    for (int k = 0; k < 4; ++k) rv[k] = rh[k * 64 + lane];
    float a0 = 0.f, a1 = 0.f;
#pragma unroll
    for (int j = 0; j < 16; ++j) {
      int k = j & 3;
      uint4 A = wa[k], B = wb[k], R = rv[k];
      if (j < 12) {
        int idx = (j + 4) * 64 + lane;
        rv[k] = rh[idx]; wa[k] = w0[idx]; wb[k] = w1[idx];
      }
      a0 = dot2(A.x, R.x, a0); a0 = dot2(A.y, R.y, a0);
      a0 = dot2(A.z, R.z, a0); a0 = dot2(A.w, R.w, a0);
      a1 = dot2(B.x, R.x, a1); a1 = dot2(B.y, R.y, a1);
      a1 = dot2(B.z, R.z, a1); a1 = dot2(B.w, R.w, a1);
    }
#pragma unroll
    for (int off = 32; off; off >>= 1) {
      a0 += __shfl_xor(a0, off);
      a1 += __shfl_xor(a1, off);
    }
    if (lane == 0) {
      float2 p = *(const float2*)(io + (size_t)t * RD + row0);
      float v0 = tanhf(a0 + p.x);
      float v1 = tanhf(a1 + p.y);
      f2 vv = { v0, v1 };
      __builtin_nontemporal_store(vv, (f2*)(io + (size_t)t * RD + row0));
      h2 hv = { (_Float16)v0, (_Float16)v1 };
      unsigned int bits = __builtin_bit_cast(unsigned int, hv);
      unsigned int* rdst = (unsigned int*)(rseq + (size_t)(MULTI ? (t + 1) : ((t + 1) & 1)) * RD + row0);
      __hip_atomic_store(rdst, bits, __ATOMIC_RELAXED, __HIP_MEMORY_SCOPE_AGENT);
    }
    asm volatile("" ::: "memory");
    __builtin_amdgcn_s_waitcnt(0x0F70);
    asm volatile("" ::: "memory");
    if (lane == 0) {
      int old = __hip_atomic_fetch_add(&lds_cnt, 1, __ATOMIC_RELAXED, __HIP_MEMORY_SCOPE_WORKGROUP);
      if (old == (t + 1) * 16 - 1) {
        int g = blockIdx.x >> 5;
        int go = __hip_atomic_fetch_add(&bar[g * 16], 1, __ATOMIC_RELAXED, __HIP_MEMORY_SCOPE_AGENT);
        if (go == (t + 1) * BLK_PER_GRP - 1) {
          int so = __hip_atomic_fetch_add(&bar[128], 1, __ATOMIC_RELAXED, __HIP_MEMORY_SCOPE_AGENT);
          if (so == (t + 1) * GRPS - 1) {
            __hip_atomic_store(&bar[160], t + 1, __ATOMIC_RELAXED, __HIP_MEMORY_SCOPE_AGENT);
          }
        }
      }
    }
    if (wave != 0) {
#pragma unroll
      for (int k = 0; k < 4; ++k) {
        int idx = k * 64 + lane;
        wa[k] = w0[idx]; wb[k] = w1[idx];
      }
      asm volatile("" ::: "memory");
      __builtin_amdgcn_s_barrier();
      asm volatile("" ::: "memory");
    } else {
      if (lane == 0) {
        while (__hip_atomic_load(&bar[160], __ATOMIC_RELAXED, __HIP_MEMORY_SCOPE_AGENT) <= t)
          __builtin_amdgcn_s_sleep(2);
        if (!MULTI)
          (void)__hip_atomic_load(&bar[160], __ATOMIC_ACQUIRE, __HIP_MEMORY_SCOPE_AGENT);
      }
      asm volatile("" ::: "memory");
      __builtin_amdgcn_s_barrier();
      asm volatile("" ::: "memory");
#pragma unroll
      for (int k = 0; k < 4; ++k) {
        int idx = k * 64 + lane;
        wa[k] = w0[idx]; wb[k] = w1[idx];
      }
    }
  }
}

// ---------- fp32 fallback (tiny ws) ----------
__device__ __forceinline__ void grid_barrier_f32(int* bar, int t, int nblk) {
  __syncthreads();
  if (threadIdx.x == 0) {
    int arrived = __hip_atomic_fetch_add(&bar[0], 1, __ATOMIC_RELEASE, __HIP_MEMORY_SCOPE_AGENT);
    if (arrived == (t + 1) * nblk - 1) {
      __hip_atomic_store(&bar[32], t + 1, __ATOMIC_RELEASE, __HIP_MEMORY_SCOPE_AGENT);
    } else {
      while (__hip_atomic_load(&bar[32], __ATOMIC_RELAXED, __HIP_MEMORY_SCOPE_AGENT) <= t)
        __builtin_amdgcn_s_sleep(2);
    }
    (void)__hip_atomic_load(&bar[32], __ATOMIC_ACQUIRE, __HIP_MEMORY_SCOPE_AGENT);
  }
  __syncthreads();
}

__global__ __launch_bounds__(1024, 4) void rollout_f32(const float* __restrict__ W,
                                                       float* __restrict__ rbuf,
                                                       float* __restrict__ io,
                                                       int* __restrict__ bar) {
  const int lane = threadIdx.x & 63;
  const int wave = threadIdx.x >> 6;
  const int row0 = blockIdx.x * 32 + wave * 2;
  const int nblk = gridDim.x;
  for (int t = 0; t < T_LEN; ++t) {
    float a0 = 0.f, a1 = 0.f;
    const float4* w0 = (const float4*)(W + (size_t)row0 * RD);
    const float4* w1 = w0 + RD / 4;
    const float4* rf = (const float4*)(rbuf + (size_t)(t & 1) * RD);
    float4 wa[4], wb[4], rv[4];
#pragma unroll
    for (int k = 0; k < 4; ++k) {
      int idx = k * 64 + lane;
      rv[k] = rf[idx]; wa[k] = w0[idx]; wb[k] = w1[idx];
    }
#pragma unroll
    for (int j = 0; j < 32; ++j) {
      int k = j & 3;
      float4 A = wa[k], B = wb[k], R = rv[k];
      if (j < 28) {
        int idx = (j + 4) * 64 + lane;
        rv[k] = rf[idx]; wa[k] = w0[idx]; wb[k] = w1[idx];
      }
      a0 += A.x * R.x + A.y * R.y + A.z * R.z + A.w * R.w;
      a1 += B.x * R.x + B.y * R.y + B.z * R.z + B.w * R.w;
    }
#pragma unroll
    for (int off = 32; off; off >>= 1) {
      a0 += __shfl_xor(a0, off);
      a1 += __shfl_xor(a1, off);
    }
    if (lane == 0) {
      float2 p = *(const float2*)(io + (size_t)t * RD + row0);
      float v0 = tanhf(a0 + p.x);
      float v1 = tanhf(a1 + p.y);
      f2 vv = { v0, v1 };
      __builtin_nontemporal_store(vv, (f2*)(io + (size_t)t * RD + row0));
      float* rn = rbuf + (size_t)((t + 1) & 1) * RD;
      *(f2*)(rn + row0) = vv;
    }
    grid_barrier_f32(bar, t, nblk);
  }
}

extern "C" void kernel_launch(void* const* d_in, const int* in_sizes, int n_in,
                              void* d_out, int out_size, void* d_ws, size_t ws_size,
                              hipStream_t stream) {
  const float* in_seq    = (const float*)d_in[0];
  const float* res_state = (const float*)d_in[1];
  const float* W_in      = (const float*)d_in[2];
  const float* W_res     = (const float*)d_in[3];
  const float* b_res     = (const float*)d_in[4];
  float* out = (float*)d_out;

  hipLaunchKernelGGL(in_proj_kernel, dim3(32, 128), dim3(256), 0, stream,
                     in_seq, W_in, b_res, out);

  const size_t w16_bytes   = (size_t)RD * RD * 2;                 // 128 MB
  const size_t rseq_multi  = (size_t)(T_LEN + 1) * RD * 2;        // 16.8 MB
  const size_t rseq_double = (size_t)2 * RD * 2;
  const size_t bar_bytes   = 1024 * 4;

  if (ws_size >= w16_bytes + rseq_multi + bar_bytes) {
    unsigned short* w16  = (unsigned short*)d_ws;
    unsigned short* rseq = (unsigned short*)((char*)d_ws + w16_bytes);
    int* bar = (int*)((char*)d_ws + w16_bytes + rseq_multi);
    hipLaunchKernelGGL(cvt_w_kernel, dim3(8192), dim3(256), 0, stream,
                       W_res, w16, (long)RD * RD);
    // sentinel-fill slots 1..T_LEN (the data-as-flag protocol)
    hipLaunchKernelGGL(fill_sentinel_kernel, dim3(2048), dim3(256), 0, stream,
                       (unsigned int*)(rseq + RD), (long)T_LEN * (RD / 2));
    hipLaunchKernelGGL(cvt_r16_kernel, dim3(RD / 256), dim3(256), 0, stream,
                       res_state, rseq, bar);
    const unsigned short* Wv = w16;
    unsigned short* rv = rseq;
    float* iov = out;
    int* barv = bar;
    void* args[4] = { &Wv, &rv, &iov, &barv };

    static int attr_done = 0;
    if (!attr_done) {
      (void)hipFuncSetAttribute((const void*)rollout_flow,
                                hipFuncAttributeMaxDynamicSharedMemorySize,
                                LDS_BYTES);
      attr_done = 1;
    }
    hipError_t err = hipLaunchCooperativeKernel(rollout_flow, dim3(NBLK),
                                                dim3(1024), args,
                                                (size_t)LDS_BYTES, stream);
    if (err != hipSuccess) {
      // dynamic-LDS refused: fall back to proven streaming kernel
      // (sentinel prefill is harmless there: every word is rewritten before read)
      (void)hipLaunchCooperativeKernel(rollout_kernel<true>, dim3(NBLK),
                                       dim3(1024), args, 0, stream);
    }
  } else if (ws_size >= w16_bytes + rseq_double + bar_bytes) {
    unsigned short* w16  = (unsigned short*)d_ws;
    unsigned short* rseq = (unsigned short*)((char*)d_ws + w16_bytes);
    int* bar = (int*)((char*)d_ws + w16_bytes + rseq_double);
    hipLaunchKernelGGL(cvt_w_kernel, dim3(8192), dim3(256), 0, stream,
                       W_res, w16, (long)RD * RD);
    hipLaunchKernelGGL(cvt_r16_kernel, dim3(RD / 256), dim3(256), 0, stream,
                       res_state, rseq, bar);
    const unsigned short* Wv = w16;
    unsigned short* rv = rseq;
    float* iov = out;
    int* barv = bar;
    void* args[4] = { &Wv, &rv, &iov, &barv };
    (void)hipLaunchCooperativeKernel(rollout_kernel<false>, dim3(NBLK), dim3(1024),
                                     args, 0, stream);
  } else {
    float* rbuf = (float*)d_ws;
    int* bar = (int*)((char*)d_ws + (size_t)2 * RD * 4);
    hipLaunchKernelGGL(cvt_r32_kernel, dim3(RD / 256), dim3(256), 0, stream,
                       res_state, rbuf, bar);
    const float* Wv = W_res;
    float* rv = rbuf;
    float* iov = out;
    int* barv = bar;
    void* args[4] = { &Wv, &rv, &iov, &barv };
    (void)hipLaunchCooperativeKernel(rollout_f32, dim3(NBLK), dim3(1024),
                                     args, 0, stream);
  }
}